// Round 1
// baseline (10326.019 us; speedup 1.0000x reference)
//
#include <hip/hip_runtime.h>
#include <hip/hip_bf16.h>
#include <stdint.h>
#include <stddef.h>

// Problem constants
#define B_SZ   4096
#define U_SZ   1024
#define K_SZ   1024
#define SEQ    5
#define TSTEPS 200

// GEMM tile config (m97-style)
#define TM  128   // batch rows per block
#define TNP 128   // packed z columns per block (= 2 wave-cols x 4 gates x 16 u)
#define BK  64

typedef __bf16 bf16_t;
typedef __bf16 bf16x8 __attribute__((ext_vector_type(8)));
typedef float  f32x4  __attribute__((ext_vector_type(4)));

#define AS1 __attribute__((address_space(1)))
#define AS3 __attribute__((address_space(3)))

__device__ __forceinline__ void load_lds16(const void* g, void* l) {
    // async global->LDS, 16B per lane; LDS dest = wave-uniform base + lane*16
    __builtin_amdgcn_global_load_lds((const AS1 unsigned int*)g,
                                     (AS3 unsigned int*)l, 16, 0, 0);
}

__device__ __forceinline__ float fsig(float x) {
    return 1.0f / (1.0f + __expf(-x));
}
__device__ __forceinline__ float ftanh(float x) {
    x = fminf(fmaxf(x, -15.0f), 15.0f);
    float e = __expf(2.0f * x);
    return (e - 1.0f) / (e + 1.0f);
}

// ---------------------------------------------------------------------------
// Pack R (1024 x 4096 fp32, row-major) into bf16 panels matching the LDS
// B-tile layout:
//   Rp[ub][kb][c][kk], ub in [0,32), kb in [0,16), c in [0,128), kk in [0,64)
//   column c maps to original n = g*1024 + ub*32 + wc*16 + cl
//     where wc = c>>6, g = (c>>4)&3, cl = c&15
// ---------------------------------------------------------------------------
__global__ void pack_R(const float* __restrict__ R, bf16_t* __restrict__ Rp) {
    int idx = blockIdx.x * 256 + threadIdx.x;   // 32*16*128*64 = 4,194,304
    int kk = idx & 63;
    int c  = (idx >> 6) & 127;
    int kb = (idx >> 13) & 15;
    int ub = idx >> 17;
    int g  = (c >> 4) & 3;
    int wc = c >> 6;
    int cl = c & 15;
    int n  = g * 1024 + ub * 32 + wc * 16 + cl;
    int k  = kb * 64 + kk;
    Rp[idx] = (bf16_t)R[(size_t)k * 4096 + n];
}

// ---------------------------------------------------------------------------
// One LSTM step: z = hin @ R + x*Wx + bias ; gates ; c,h update (fused).
// Grid: (32 batch-tiles, 32 u-tiles), 256 threads (4 waves, 2x2 of 64x64).
// ---------------------------------------------------------------------------
__global__ __launch_bounds__(256, 2)
void lstm_step(const bf16_t* __restrict__ hin,
               bf16_t* __restrict__ hout,
               float* __restrict__ cst,
               const bf16_t* __restrict__ Rp,
               const float* __restrict__ Wx,     // kernel, (1,4096)
               const float* __restrict__ bias,   // (4096,)
               const float* __restrict__ xsrc, int xstride)
{
    __shared__ __align__(16) bf16_t lsA[TM * BK];    // 16 KB
    __shared__ __align__(16) bf16_t lsB[TNP * BK];   // 16 KB
    __shared__ float lsX[TM];

    const int tid  = threadIdx.x;
    const int wave = tid >> 6;
    const int lane = tid & 63;
    const int mb   = blockIdx.x;
    const int ub   = blockIdx.y;

    if (tid < TM) lsX[tid] = xsrc[(size_t)(mb * TM + tid) * xstride];

    f32x4 acc[4][4] = {};

    const bf16_t* Apanel = hin + (size_t)mb * TM * K_SZ;
    const bf16_t* Bpanel = Rp + (size_t)ub * 16 * (TNP * BK);

    const int rbase = (wave >> 1) * 64;
    const int cbase = (wave & 1) * 64;
    const int l15   = lane & 15;

    for (int kb = 0; kb < K_SZ / BK; ++kb) {
        // stage A: 16 KB, 4 x 1KB chunks per wave; [m][kk] rows of 64 bf16
        #pragma unroll
        for (int i = 0; i < 4; ++i) {
            int chunk = wave * 4 + i;
            int m  = chunk * 8 + (lane >> 3);
            int kk = (lane & 7) * 8;
            const bf16_t* g = Apanel + (size_t)m * K_SZ + kb * BK + kk;
            load_lds16(g, &lsA[chunk * 512]);
        }
        // stage B: straight 16 KB copy (panel layout == LDS layout, [c][kk])
        const bf16_t* Bp = Bpanel + kb * (TNP * BK);
        #pragma unroll
        for (int i = 0; i < 4; ++i) {
            int chunk = wave * 4 + i;
            const bf16_t* g = Bp + chunk * 512 + lane * 8;
            load_lds16(g, &lsB[chunk * 512]);
        }
        __syncthreads();

        #pragma unroll
        for (int kh = 0; kh < 2; ++kh) {
            int ko = kh * 32 + ((lane >> 4) << 3);
            bf16x8 af[4], bfr[4];
            #pragma unroll
            for (int mi = 0; mi < 4; ++mi)
                af[mi] = *(const bf16x8*)&lsA[(rbase + mi * 16 + l15) * BK + ko];
            #pragma unroll
            for (int ni = 0; ni < 4; ++ni)
                bfr[ni] = *(const bf16x8*)&lsB[(cbase + ni * 16 + l15) * BK + ko];
            #pragma unroll
            for (int mi = 0; mi < 4; ++mi)
                #pragma unroll
                for (int ni = 0; ni < 4; ++ni)
                    acc[mi][ni] = __builtin_amdgcn_mfma_f32_16x16x32_bf16(
                        af[mi], bfr[ni], acc[mi][ni], 0, 0, 0);
        }
        __syncthreads();
    }

    // Epilogue: lane's acc[mi][ni][r] holds z at
    //   row = rbase + mi*16 + (lane>>4)*4 + r,  gate = ni,  u = ub*32 + wc*16 + (lane&15)
    const int wc = wave & 1;
    const int u  = ub * 32 + wc * 16 + l15;

    const float bi = bias[u],        wi = Wx[u];
    const float bf = bias[1024 + u], wf = Wx[1024 + u];
    const float bg = bias[2048 + u], wg = Wx[2048 + u];
    const float bo = bias[3072 + u], wo = Wx[3072 + u];
    const int rquad = (lane >> 4) << 2;

    #pragma unroll
    for (int mi = 0; mi < 4; ++mi) {
        int rlocal = rbase + mi * 16 + rquad;
        #pragma unroll
        for (int r = 0; r < 4; ++r) {
            int    brow = mb * TM + rlocal + r;
            float  xv   = lsX[rlocal + r];
            float zi = acc[mi][0][r] + bi + xv * wi;
            float zf = acc[mi][1][r] + bf + xv * wf;
            float zg = acc[mi][2][r] + bg + xv * wg;
            float zo = acc[mi][3][r] + bo + xv * wo;
            float ig = fsig(zi);
            float fg = fsig(zf);
            float gg = ftanh(zg);
            float og = fsig(zo);
            size_t off = (size_t)brow * U_SZ + u;
            float cn = fg * cst[off] + ig * gg;
            cst[off]  = cn;
            hout[off] = (bf16_t)(og * ftanh(cn));
        }
    }
}

// ---------------------------------------------------------------------------
// pred / output: x1 = relu(h@w1 + b1); mode 0: p = x1 (first output);
// mode 1: p = x1*w2 + b2. Writes pred[b] (feedback) and out[b*200 + t].
// ---------------------------------------------------------------------------
__global__ __launch_bounds__(256)
void pred_step(const bf16_t* __restrict__ h, const float* __restrict__ w1,
               const float* __restrict__ b1, const float* __restrict__ w2,
               const float* __restrict__ b2, float* __restrict__ pred,
               float* __restrict__ out, int t, int mode)
{
    int b   = blockIdx.x;
    int tid = threadIdx.x;
    const bf16_t* hr = h + (size_t)b * U_SZ;
    float s = 0.f;
    #pragma unroll
    for (int j = 0; j < 4; ++j) {
        int idx = tid + j * 256;
        s += (float)hr[idx] * w1[idx];
    }
    #pragma unroll
    for (int off = 32; off > 0; off >>= 1)
        s += __shfl_down(s, off, 64);
    __shared__ float red[4];
    if ((tid & 63) == 0) red[tid >> 6] = s;
    __syncthreads();
    if (tid == 0) {
        float x1 = red[0] + red[1] + red[2] + red[3] + b1[0];
        x1 = fmaxf(x1, 0.f);
        float p = mode ? (x1 * w2[0] + b2[0]) : x1;
        pred[b] = p;
        out[(size_t)b * TSTEPS + t] = p;
    }
}

extern "C" void kernel_launch(void* const* d_in, const int* in_sizes, int n_in,
                              void* d_out, int out_size, void* d_ws, size_t ws_size,
                              hipStream_t stream) {
    const float* inputs = (const float*)d_in[0];   // [4096,5,1]
    const float* Wx     = (const float*)d_in[1];   // [1,4096]
    const float* R      = (const float*)d_in[2];   // [1024,4096]
    const float* bias   = (const float*)d_in[3];   // [4096]
    const float* w1     = (const float*)d_in[4];   // [1024,1]
    const float* b1     = (const float*)d_in[5];
    const float* w2     = (const float*)d_in[6];
    const float* b2     = (const float*)d_in[7];
    float* out = (float*)d_out;

    char* ws = (char*)d_ws;
    const size_t RP_BYTES = (size_t)32 * 16 * 128 * 64 * 2;   // 8,388,608
    const size_t H_BYTES  = (size_t)B_SZ * U_SZ * 2;          // 8,388,608
    const size_t C_BYTES  = (size_t)B_SZ * U_SZ * 4;          // 16,777,216
    bf16_t* Rp   = (bf16_t*)ws;                 ws += RP_BYTES;
    bf16_t* h0   = (bf16_t*)ws;                 ws += H_BYTES;
    bf16_t* h1   = (bf16_t*)ws;                 ws += H_BYTES;
    float*  cbuf = (float*)ws;                  ws += C_BYTES;
    float*  pred = (float*)ws;                  ws += (size_t)B_SZ * 4;
    bf16_t* hb[2] = {h0, h1};

    hipMemsetAsync(h0, 0, H_BYTES, stream);
    hipMemsetAsync(cbuf, 0, C_BYTES, stream);

    pack_R<<<16384, 256, 0, stream>>>(R, Rp);

    dim3 grid(B_SZ / TM, U_SZ / 32);  // (32, 32)
    int cur = 0;
    // warmup over the input sequence
    for (int t = 0; t < SEQ; ++t) {
        lstm_step<<<grid, 256, 0, stream>>>(hb[cur], hb[1 - cur], cbuf, Rp, Wx,
                                            bias, inputs + t, SEQ);
        cur ^= 1;
    }
    pred_step<<<B_SZ, 256, 0, stream>>>(hb[cur], w1, b1, w2, b2, pred, out, 0, 0);
    // autoregressive decode
    for (int t = 1; t < TSTEPS; ++t) {
        lstm_step<<<grid, 256, 0, stream>>>(hb[cur], hb[1 - cur], cbuf, Rp, Wx,
                                            bias, pred, 1);
        cur ^= 1;
        pred_step<<<B_SZ, 256, 0, stream>>>(hb[cur], w1, b1, w2, b2, pred, out, t, 1);
    }
}

// Round 3
// 10062.601 us; speedup vs baseline: 1.0262x; 1.0262x over previous
//
#include <hip/hip_runtime.h>
#include <hip/hip_bf16.h>
#include <stdint.h>
#include <stddef.h>

#define B_SZ   4096
#define U_SZ   1024
#define SEQ    5
#define TSTEPS 200
#define STEPS  204          // 5 warmup + 199 decode LSTM steps

typedef __bf16 bf16_t;
typedef __bf16 bf16x8 __attribute__((ext_vector_type(8)));
typedef float  f32x4  __attribute__((ext_vector_type(4)));

#define AS1 __attribute__((address_space(1)))
#define AS3 __attribute__((address_space(3)))

#define LOAD_LDS16(gp, lp) \
    __builtin_amdgcn_global_load_lds((const AS1 unsigned int*)(gp), \
                                     (AS3 unsigned int*)(lp), 16, 0, 0)

__device__ __forceinline__ float fsig(float x) {
    return 1.0f / (1.0f + __expf(-x));
}
__device__ __forceinline__ float ftanh(float x) {
    x = fminf(fmaxf(x, -15.0f), 15.0f);
    float e = __expf(2.0f * x);
    return (e - 1.0f) / (e + 1.0f);
}

// ---------------------------------------------------------------------------
// Pack R (1024 x 4096 fp32 row-major) into bf16 panels, one per ub (32 u's):
//   Rp[ub][kb][c][kk], kb<16, c<128, kk<64 ;
//   col c -> n = g*1024 + ub*32 + wc*16 + cl  (wc=c>>6, g=(c>>4)&3, cl=c&15)
// ---------------------------------------------------------------------------
__global__ void pack_R(const float* __restrict__ R, bf16_t* __restrict__ Rp) {
    int idx = blockIdx.x * 256 + threadIdx.x;   // 4,194,304 total
    int kk = idx & 63;
    int c  = (idx >> 6) & 127;
    int kb = (idx >> 13) & 15;
    int ub = idx >> 17;
    int g  = (c >> 4) & 3;
    int wc = c >> 6;
    int cl = c & 15;
    int n  = g * 1024 + ub * 32 + wc * 16 + cl;
    int k  = kb * 64 + kk;
    Rp[idx] = (bf16_t)R[(size_t)k * 4096 + n];
}

// ---------------------------------------------------------------------------
// One LSTM step, dual-panel blocks + fused pred partial sums.
// Grid (16,32): p = blockIdx.x covers panels {2p,2p+1} (64 u's), G = blockIdx.y
// covers batch rows G*128..+128.  p fastest -> XCD = bid%8 keyed to p -> each
// XCD's B panels (1 MB) stay L2-resident. praw: 3 rotating 4096-float buffers:
//   step t accumulates t%3, reads (t+2)%3 (=t-1), zeroes (t+1)%3.
// ---------------------------------------------------------------------------
__global__ __launch_bounds__(256, 2)
void lstm_step(const bf16_t* __restrict__ hin,
               bf16_t* __restrict__ hout,
               float* __restrict__ cst,
               const bf16_t* __restrict__ Rp,
               const float* __restrict__ Wx,     // (4096,)
               const float* __restrict__ bias,   // (4096,)
               const float* __restrict__ w1,     // (1024,)
               const float* __restrict__ b1,
               const float* __restrict__ w2,
               const float* __restrict__ b2,
               const float* __restrict__ inputs, // [4096,5]
               float* __restrict__ praw,         // 3*4096
               float* __restrict__ out,          // [4096,200]
               int t)
{
    __shared__ __align__(16) bf16_t lsA[128 * 64];       // 16 KB
    __shared__ __align__(16) bf16_t lsB[2][128 * 64];    // 32 KB
    __shared__ float lsX[128];

    const int tid  = threadIdx.x;
    const int wave = tid >> 6;
    const int lane = tid & 63;
    const int p    = blockIdx.x;   // 0..15
    const int G    = blockIdx.y;   // 0..31
    const int l15  = lane & 15;
    const int quad = lane >> 4;
    const int rbase = (wave >> 1) * 64;
    const int wc    = wave & 1;

    float*       pr_acc  = praw + (size_t)(t % 3) * B_SZ;
    const float* pr_read = praw + (size_t)((t + 2) % 3) * B_SZ;
    float*       pr_zero = praw + (size_t)((t + 1) % 3) * B_SZ;

    // ---- prologue: x for my 128 rows (+ out write + praw-slot zero) ----
    if (tid < 128) {
        int row = G * 128 + tid;
        float x;
        if (t < SEQ) {
            x = inputs[row * SEQ + t];
        } else {
            float x1 = fmaxf(pr_read[row] + b1[0], 0.f);
            x = (t == SEQ) ? x1 : x1 * w2[0] + b2[0];
            if (p == 0) out[(size_t)row * TSTEPS + (t - SEQ)] = x;
        }
        lsX[tid] = x;
        if (p == 0) pr_zero[row] = 0.f;
    }

    // ---- dual-panel K-loop: z = hin @ [Rp(2p), Rp(2p+1)] ----
    f32x4 acc[2][4][4] = {};
    const bf16_t* Ap  = hin + (size_t)G * 128 * U_SZ;
    const bf16_t* Bp0 = Rp + (size_t)(2 * p) * 131072;
    const bf16_t* Bp1 = Bp0 + 131072;

    for (int kb = 0; kb < 16; ++kb) {
        #pragma unroll
        for (int i = 0; i < 4; ++i) {           // A: 16 KB
            int chunk = wave * 4 + i;
            int m  = chunk * 8 + (lane >> 3);
            int kk = (lane & 7) * 8;
            LOAD_LDS16(Ap + (size_t)m * U_SZ + kb * 64 + kk, &lsA[chunk * 512]);
        }
        #pragma unroll
        for (int i = 0; i < 4; ++i) {           // B: 2 x 16 KB (straight copy)
            int chunk = wave * 4 + i;
            LOAD_LDS16(Bp0 + (size_t)kb * 8192 + chunk * 512 + lane * 8,
                       &lsB[0][chunk * 512]);
            LOAD_LDS16(Bp1 + (size_t)kb * 8192 + chunk * 512 + lane * 8,
                       &lsB[1][chunk * 512]);
        }
        __syncthreads();

        #pragma unroll
        for (int kh = 0; kh < 2; ++kh) {
            int ko = kh * 32 + quad * 8;
            bf16x8 af[4];
            #pragma unroll
            for (int mi = 0; mi < 4; ++mi)
                af[mi] = *(const bf16x8*)&lsA[(rbase + mi * 16 + l15) * 64 + ko];
            #pragma unroll
            for (int T = 0; T < 2; ++T) {
                bf16x8 bfr[4];
                #pragma unroll
                for (int ni = 0; ni < 4; ++ni)
                    bfr[ni] = *(const bf16x8*)
                        &lsB[T][(wc * 64 + ni * 16 + l15) * 64 + ko];
                #pragma unroll
                for (int mi = 0; mi < 4; ++mi)
                    #pragma unroll
                    for (int ni = 0; ni < 4; ++ni)
                        acc[T][mi][ni] = __builtin_amdgcn_mfma_f32_16x16x32_bf16(
                            af[mi], bfr[ni], acc[T][mi][ni], 0, 0, 0);
            }
        }
        __syncthreads();
    }

    // ---- epilogue: gates, c RMW (global fp32), h write, pred partials ----
    int uu[2];
    uu[0] = (2 * p) * 32 + wc * 16 + l15;
    uu[1] = uu[0] + 32;
    float g_b[2][4], g_w[2][4], w1u[2];
    #pragma unroll
    for (int T = 0; T < 2; ++T) {
        #pragma unroll
        for (int g = 0; g < 4; ++g) {
            g_b[T][g] = bias[g * 1024 + uu[T]];
            g_w[T][g] = Wx[g * 1024 + uu[T]];
        }
        w1u[T] = w1[uu[T]];
    }
    const bool do_pred = (t >= SEQ - 1);

    #pragma unroll
    for (int mi = 0; mi < 4; ++mi) {
        #pragma unroll
        for (int r = 0; r < 4; ++r) {
            int rl   = rbase + mi * 16 + quad * 4 + r;
            int brow = G * 128 + rl;
            float xv = lsX[rl];
            float ps = 0.f;
            #pragma unroll
            for (int T = 0; T < 2; ++T) {
                float zi = acc[T][mi][0][r] + g_b[T][0] + xv * g_w[T][0];
                float zf = acc[T][mi][1][r] + g_b[T][1] + xv * g_w[T][1];
                float zg = acc[T][mi][2][r] + g_b[T][2] + xv * g_w[T][2];
                float zo = acc[T][mi][3][r] + g_b[T][3] + xv * g_w[T][3];
                float ig = fsig(zi), fg = fsig(zf);
                float gg = ftanh(zg), og = fsig(zo);
                size_t off = (size_t)brow * U_SZ + uu[T];
                float cn = fg * cst[off] + ig * gg;
                cst[off] = cn;
                float hv = og * ftanh(cn);
                hout[off] = (bf16_t)hv;
                ps += hv * w1u[T];
            }
            if (do_pred) {
                ps += __shfl_xor(ps, 1);
                ps += __shfl_xor(ps, 2);
                ps += __shfl_xor(ps, 4);
                ps += __shfl_xor(ps, 8);
                if (l15 == 0) atomicAdd(&pr_acc[brow], ps);
            }
        }
    }
}

// final output slot 199 from praw of step 203 (203 % 3 == 2)
__global__ void pred_final(const float* __restrict__ praw,
                           const float* __restrict__ b1,
                           const float* __restrict__ w2,
                           const float* __restrict__ b2,
                           float* __restrict__ out)
{
    int row = blockIdx.x * 256 + threadIdx.x;
    float x1 = fmaxf(praw[2 * B_SZ + row] + b1[0], 0.f);
    out[(size_t)row * TSTEPS + 199] = x1 * w2[0] + b2[0];
}

extern "C" void kernel_launch(void* const* d_in, const int* in_sizes, int n_in,
                              void* d_out, int out_size, void* d_ws, size_t ws_size,
                              hipStream_t stream) {
    const float* inputs = (const float*)d_in[0];   // [4096,5,1]
    const float* Wx     = (const float*)d_in[1];   // [1,4096]
    const float* R      = (const float*)d_in[2];   // [1024,4096]
    const float* bias   = (const float*)d_in[3];   // [4096]
    const float* w1     = (const float*)d_in[4];   // [1024,1]
    const float* b1     = (const float*)d_in[5];
    const float* w2     = (const float*)d_in[6];
    const float* b2     = (const float*)d_in[7];
    float* out = (float*)d_out;

    char* ws = (char*)d_ws;
    const size_t RP_BYTES = (size_t)32 * 131072 * 2;          // 8 MB
    const size_t H_BYTES  = (size_t)B_SZ * U_SZ * 2;          // 8 MB
    const size_t C_BYTES  = (size_t)B_SZ * U_SZ * 4;          // 16 MB
    bf16_t* Rp   = (bf16_t*)ws;                ws += RP_BYTES;
    bf16_t* h0   = (bf16_t*)ws;                ws += H_BYTES;
    bf16_t* h1   = (bf16_t*)ws;                ws += H_BYTES;
    float*  cbuf = (float*)ws;                 ws += C_BYTES;
    float*  praw = (float*)ws;                 ws += 3 * B_SZ * 4;
    bf16_t* hb[2] = {h0, h1};

    hipMemsetAsync(h0, 0, H_BYTES, stream);
    hipMemsetAsync(cbuf, 0, C_BYTES, stream);
    hipMemsetAsync(praw, 0, 3 * B_SZ * 4, stream);

    pack_R<<<16384, 256, 0, stream>>>(R, Rp);

    dim3 grid(16, 32);   // p fastest -> B panels pinned per XCD
    int cur = 0;
    for (int t = 0; t < STEPS; ++t) {
        lstm_step<<<grid, 256, 0, stream>>>(hb[cur], hb[1 - cur], cbuf, Rp,
                                            Wx, bias, w1, b1, w2, b2,
                                            inputs, praw, out, t);
        cur ^= 1;
    }
    pred_final<<<16, 256, 0, stream>>>(praw, b1, w2, b2, out);
}

// Round 4
// 8704.602 us; speedup vs baseline: 1.1863x; 1.1560x over previous
//
#include <hip/hip_runtime.h>
#include <hip/hip_bf16.h>
#include <stdint.h>
#include <stddef.h>

#define B_SZ   4096
#define U_SZ   1024
#define SEQ    5
#define TSTEPS 200
#define STEPS  204          // 5 warmup + 199 decode LSTM steps

typedef __bf16 bf16_t;
typedef __bf16 bf16x8 __attribute__((ext_vector_type(8)));
typedef float  f32x4  __attribute__((ext_vector_type(4)));

#define AS1 __attribute__((address_space(1)))
#define AS3 __attribute__((address_space(3)))

#define LOAD_LDS16(gp, lp) \
    __builtin_amdgcn_global_load_lds((const AS1 unsigned int*)(gp), \
                                     (AS3 unsigned int*)(lp), 16, 0, 0)

__device__ __forceinline__ float fsig(float x) {
    return 1.0f / (1.0f + __expf(-x));
}
__device__ __forceinline__ float ftanh(float x) {
    x = fminf(fmaxf(x, -15.0f), 15.0f);
    float e = __expf(2.0f * x);
    return (e - 1.0f) / (e + 1.0f);
}

// ---------------------------------------------------------------------------
// Pack R (1024 x 4096 fp32 row-major) into bf16 panels, one per ub (32 u's),
// with XOR-swizzled 16B slots to kill LDS bank conflicts:
//   Rp[ub][kb][c][phys_slot][e]  (kb<16, c<128, phys_slot<8, e<8)
//   logical k-slot = phys_slot ^ (c & 7)
//   col c -> n = g*1024 + ub*32 + wc*16 + cl  (wc=c>>6, g=(c>>4)&3, cl=c&15)
// ---------------------------------------------------------------------------
__global__ void pack_R(const float* __restrict__ R, bf16_t* __restrict__ Rp) {
    int idx = blockIdx.x * 256 + threadIdx.x;   // 4,194,304 total
    int e    = idx & 7;
    int slot = (idx >> 3) & 7;                  // physical 16B slot in row
    int c    = (idx >> 6) & 127;
    int kb   = (idx >> 13) & 15;
    int ub   = idx >> 17;
    int g  = (c >> 4) & 3;
    int wc = c >> 6;
    int cl = c & 15;
    int n  = g * 1024 + ub * 32 + wc * 16 + cl;
    int k  = kb * 64 + ((slot ^ (c & 7)) << 3) + e;   // un-swizzle -> logical k
    Rp[idx] = (bf16_t)R[(size_t)k * 4096 + n];
}

// ---------------------------------------------------------------------------
// One LSTM step, dual-panel blocks + fused pred partial sums.
// Grid (16,32): p = blockIdx.x covers panels {2p,2p+1}, G = blockIdx.y covers
// batch rows G*128..+128.  p fastest -> bid%8 keyed to p -> B panels pinned
// per XCD L2.  LDS rows (128B) are XOR-swizzled: phys16Bslot = s ^ (row&7).
// ---------------------------------------------------------------------------
__global__ __launch_bounds__(256, 2)
void lstm_step(const bf16_t* __restrict__ hin,
               bf16_t* __restrict__ hout,
               float* __restrict__ cst,
               const bf16_t* __restrict__ Rp,
               const float* __restrict__ Wx,     // (4096,)
               const float* __restrict__ bias,   // (4096,)
               const float* __restrict__ w1,     // (1024,)
               const float* __restrict__ b1,
               const float* __restrict__ w2,
               const float* __restrict__ b2,
               const float* __restrict__ inputs, // [4096,5]
               float* __restrict__ praw,         // 3*4096
               float* __restrict__ out,          // [4096,200]
               int t)
{
    __shared__ __align__(16) bf16_t lsA[128 * 64];       // 16 KB
    __shared__ __align__(16) bf16_t lsB[2][128 * 64];    // 32 KB
    __shared__ float lsX[128];

    const int tid  = threadIdx.x;
    const int wave = tid >> 6;
    const int lane = tid & 63;
    const int p    = blockIdx.x;   // 0..15
    const int G    = blockIdx.y;   // 0..31
    const int l15  = lane & 15;
    const int quad = lane >> 4;
    const int rbase = (wave >> 1) * 64;
    const int wc    = wave & 1;

    float*       pr_acc  = praw + (size_t)(t % 3) * B_SZ;
    const float* pr_read = praw + (size_t)((t + 2) % 3) * B_SZ;
    float*       pr_zero = praw + (size_t)((t + 1) % 3) * B_SZ;

    // ---- prologue: x for my 128 rows (+ out write + praw-slot zero) ----
    if (tid < 128) {
        int row = G * 128 + tid;
        float x;
        if (t < SEQ) {
            x = inputs[row * SEQ + t];
        } else {
            float x1 = fmaxf(pr_read[row] + b1[0], 0.f);
            x = (t == SEQ) ? x1 : x1 * w2[0] + b2[0];
            if (p == 0) out[(size_t)row * TSTEPS + (t - SEQ)] = x;
        }
        lsX[tid] = x;
        if (p == 0) pr_zero[row] = 0.f;
    }

    // ---- dual-panel K-loop: z = hin @ [Rp(2p), Rp(2p+1)] ----
    f32x4 acc[2][4][4] = {};
    const bf16_t* Ap  = hin + (size_t)G * 128 * U_SZ;
    const bf16_t* Bp0 = Rp + (size_t)(2 * p) * 131072;
    const bf16_t* Bp1 = Bp0 + 131072;

    // A staging source k-offset: lane writes phys slot (lane&7) of row
    // (chunk*8 + (lane>>3)); logical slot = (lane&7) ^ (lane>>3).
    const int a_kk = (((lane & 7) ^ (lane >> 3)) << 3);

    for (int kb = 0; kb < 16; ++kb) {
        #pragma unroll
        for (int i = 0; i < 4; ++i) {           // A: 16 KB (swizzled source)
            int chunk = wave * 4 + i;
            int m  = chunk * 8 + (lane >> 3);
            LOAD_LDS16(Ap + (size_t)m * U_SZ + kb * 64 + a_kk, &lsA[chunk * 512]);
        }
        #pragma unroll
        for (int i = 0; i < 4; ++i) {           // B: 2 x 16 KB (straight copy)
            int chunk = wave * 4 + i;
            LOAD_LDS16(Bp0 + (size_t)kb * 8192 + chunk * 512 + lane * 8,
                       &lsB[0][chunk * 512]);
            LOAD_LDS16(Bp1 + (size_t)kb * 8192 + chunk * 512 + lane * 8,
                       &lsB[1][chunk * 512]);
        }
        __syncthreads();

        #pragma unroll
        for (int kh = 0; kh < 2; ++kh) {
            // logical slot s = kh*4+quad; phys = s ^ (row&7), row&7 == lane&7
            int sw = (((kh * 4 + quad) ^ (lane & 7)) << 3);
            bf16x8 af[4];
            #pragma unroll
            for (int mi = 0; mi < 4; ++mi)
                af[mi] = *(const bf16x8*)&lsA[(rbase + mi * 16 + l15) * 64 + sw];
            #pragma unroll
            for (int T = 0; T < 2; ++T) {
                bf16x8 bfr[4];
                #pragma unroll
                for (int ni = 0; ni < 4; ++ni)
                    bfr[ni] = *(const bf16x8*)
                        &lsB[T][(wc * 64 + ni * 16 + l15) * 64 + sw];
                #pragma unroll
                for (int mi = 0; mi < 4; ++mi)
                    #pragma unroll
                    for (int ni = 0; ni < 4; ++ni)
                        acc[T][mi][ni] = __builtin_amdgcn_mfma_f32_16x16x32_bf16(
                            af[mi], bfr[ni], acc[T][mi][ni], 0, 0, 0);
            }
        }
        __syncthreads();
    }

    // ---- epilogue: gates, c RMW (global fp32), h write, pred partials ----
    int uu[2];
    uu[0] = (2 * p) * 32 + wc * 16 + l15;
    uu[1] = uu[0] + 32;
    float g_b[2][4], g_w[2][4], w1u[2];
    #pragma unroll
    for (int T = 0; T < 2; ++T) {
        #pragma unroll
        for (int g = 0; g < 4; ++g) {
            g_b[T][g] = bias[g * 1024 + uu[T]];
            g_w[T][g] = Wx[g * 1024 + uu[T]];
        }
        w1u[T] = w1[uu[T]];
    }
    const bool do_pred = (t >= SEQ - 1);

    #pragma unroll
    for (int mi = 0; mi < 4; ++mi) {
        #pragma unroll
        for (int r = 0; r < 4; ++r) {
            int rl   = rbase + mi * 16 + quad * 4 + r;
            int brow = G * 128 + rl;
            float xv = lsX[rl];
            float ps = 0.f;
            #pragma unroll
            for (int T = 0; T < 2; ++T) {
                float zi = acc[T][mi][0][r] + g_b[T][0] + xv * g_w[T][0];
                float zf = acc[T][mi][1][r] + g_b[T][1] + xv * g_w[T][1];
                float zg = acc[T][mi][2][r] + g_b[T][2] + xv * g_w[T][2];
                float zo = acc[T][mi][3][r] + g_b[T][3] + xv * g_w[T][3];
                float ig = fsig(zi), fg = fsig(zf);
                float gg = ftanh(zg), og = fsig(zo);
                size_t off = (size_t)brow * U_SZ + uu[T];
                float cn = fg * cst[off] + ig * gg;
                cst[off] = cn;
                float hv = og * ftanh(cn);
                hout[off] = (bf16_t)hv;
                ps += hv * w1u[T];
            }
            if (do_pred) {
                ps += __shfl_xor(ps, 1);
                ps += __shfl_xor(ps, 2);
                ps += __shfl_xor(ps, 4);
                ps += __shfl_xor(ps, 8);
                if (l15 == 0) atomicAdd(&pr_acc[brow], ps);
            }
        }
    }
}

// final output slot 199 from praw of step 203 (203 % 3 == 2)
__global__ void pred_final(const float* __restrict__ praw,
                           const float* __restrict__ b1,
                           const float* __restrict__ w2,
                           const float* __restrict__ b2,
                           float* __restrict__ out)
{
    int row = blockIdx.x * 256 + threadIdx.x;
    float x1 = fmaxf(praw[2 * B_SZ + row] + b1[0], 0.f);
    out[(size_t)row * TSTEPS + 199] = x1 * w2[0] + b2[0];
}

extern "C" void kernel_launch(void* const* d_in, const int* in_sizes, int n_in,
                              void* d_out, int out_size, void* d_ws, size_t ws_size,
                              hipStream_t stream) {
    const float* inputs = (const float*)d_in[0];   // [4096,5,1]
    const float* Wx     = (const float*)d_in[1];   // [1,4096]
    const float* R      = (const float*)d_in[2];   // [1024,4096]
    const float* bias   = (const float*)d_in[3];   // [4096]
    const float* w1     = (const float*)d_in[4];   // [1024,1]
    const float* b1     = (const float*)d_in[5];
    const float* w2     = (const float*)d_in[6];
    const float* b2     = (const float*)d_in[7];
    float* out = (float*)d_out;

    char* ws = (char*)d_ws;
    const size_t RP_BYTES = (size_t)32 * 131072 * 2;          // 8 MB
    const size_t H_BYTES  = (size_t)B_SZ * U_SZ * 2;          // 8 MB
    const size_t C_BYTES  = (size_t)B_SZ * U_SZ * 4;          // 16 MB
    bf16_t* Rp   = (bf16_t*)ws;                ws += RP_BYTES;
    bf16_t* h0   = (bf16_t*)ws;                ws += H_BYTES;
    bf16_t* h1   = (bf16_t*)ws;                ws += H_BYTES;
    float*  cbuf = (float*)ws;                 ws += C_BYTES;
    float*  praw = (float*)ws;                 ws += 3 * B_SZ * 4;
    bf16_t* hb[2] = {h0, h1};

    hipMemsetAsync(h0, 0, H_BYTES, stream);
    hipMemsetAsync(cbuf, 0, C_BYTES, stream);
    hipMemsetAsync(praw, 0, 3 * B_SZ * 4, stream);

    pack_R<<<16384, 256, 0, stream>>>(R, Rp);

    dim3 grid(16, 32);   // p fastest -> B panels pinned per XCD
    int cur = 0;
    for (int t = 0; t < STEPS; ++t) {
        lstm_step<<<grid, 256, 0, stream>>>(hb[cur], hb[1 - cur], cbuf, Rp,
                                            Wx, bias, w1, b1, w2, b2,
                                            inputs, praw, out, t);
        cur ^= 1;
    }
    pred_final<<<16, 256, 0, stream>>>(praw, b1, w2, b2, out);
}